// Round 1
// baseline (928.469 us; speedup 1.0000x reference)
//
#include <hip/hip_runtime.h>
#include <hip/hip_bf16.h>
#include <cstdint>

#define DEV static __device__ __forceinline__

typedef __attribute__((ext_vector_type(8))) __bf16 bf16x8;
typedef __attribute__((ext_vector_type(4))) float f32x4;
typedef __attribute__((ext_vector_type(8))) unsigned short ushort8;

constexpr int NTOK = 65536;
constexpr int E = 1024;

DEV unsigned short f2b(float f) {
  unsigned int u = __builtin_bit_cast(unsigned int, f);
  u += 0x7fffu + ((u >> 16) & 1u);
  return (unsigned short)(u >> 16);
}

DEV f32x4 mfma16(bf16x8 a, bf16x8 b, f32x4 c) {
  return __builtin_amdgcn_mfma_f32_16x16x32_bf16(a, b, c, 0, 0, 0);
}

DEV void gload16(const void* g, void* l) {
  __builtin_amdgcn_global_load_lds(
      (const __attribute__((address_space(1))) void*)g,
      (__attribute__((address_space(3))) void*)l, 16, 0, 0);
}

// ---------------- fp32 -> bf16 convert, 8 elems/thread ----------------
__global__ void cvt8(const float* __restrict__ in, unsigned short* __restrict__ out,
                     int n8) {
  int i = blockIdx.x * blockDim.x + threadIdx.x;
  if (i >= n8) return;
  const float4* p = (const float4*)(in + (size_t)i * 8);
  float4 a = p[0], b = p[1];
  ushort8 r;
  r[0] = f2b(a.x); r[1] = f2b(a.y); r[2] = f2b(a.z); r[3] = f2b(a.w);
  r[4] = f2b(b.x); r[5] = f2b(b.y); r[6] = f2b(b.z); r[7] = f2b(b.w);
  *(ushort8*)(out + (size_t)i * 8) = r;
}

// ---------------- C[M,N] = A[M,K] * B[N,K]^T  (bf16 in, OutT out) ------------
// m97 structure: 128x128 tile, BK=32, 4 waves (each 64x64 = 4x4 of 16x16 MFMA),
// global_load_lds width-16 staging, 2-barrier K-loop.
template <typename OutT>
__global__ __launch_bounds__(256, 2) void gemm_bt(
    const unsigned short* __restrict__ A, const unsigned short* __restrict__ B,
    OutT* __restrict__ C, int M, int N, int K) {
  __shared__ unsigned short As[128 * 32];
  __shared__ unsigned short Bs[128 * 32];
  const int t = threadIdx.x;
  const int w = t >> 6, l = t & 63;
  const int tm = blockIdx.y * 128, tn = blockIdx.x * 128;
  const int wr = (w >> 1) * 64, wc = (w & 1) * 64;
  const int lr = l & 15, lk = (l >> 4) * 8;
  const int srow = w * 16 + (l >> 2);  // staging row within a 64-row half
  const int scol = (l & 3) * 8;
  const unsigned short* Ab = A + (size_t)tm * K;
  const unsigned short* Bb = B + (size_t)tn * K;
  char* AsB = (char*)As;
  char* BsB = (char*)Bs;
  f32x4 acc[4][4] = {};
  for (int k0 = 0; k0 < K; k0 += 32) {
    gload16(Ab + (size_t)srow * K + k0 + scol, AsB + w * 1024);
    gload16(Ab + (size_t)(64 + srow) * K + k0 + scol, AsB + 4096 + w * 1024);
    gload16(Bb + (size_t)srow * K + k0 + scol, BsB + w * 1024);
    gload16(Bb + (size_t)(64 + srow) * K + k0 + scol, BsB + 4096 + w * 1024);
    __syncthreads();  // compiler emits vmcnt(0) drain before s_barrier
    bf16x8 af[4], bn[4];
#pragma unroll
    for (int m = 0; m < 4; ++m)
      af[m] = *reinterpret_cast<const bf16x8*>(&As[(wr + m * 16 + lr) * 32 + lk]);
#pragma unroll
    for (int n = 0; n < 4; ++n)
      bn[n] = *reinterpret_cast<const bf16x8*>(&Bs[(wc + n * 16 + lr) * 32 + lk]);
#pragma unroll
    for (int m = 0; m < 4; ++m)
#pragma unroll
      for (int n = 0; n < 4; ++n)
        acc[m][n] = mfma16(af[m], bn[n], acc[m][n]);
    __syncthreads();
  }
#pragma unroll
  for (int m = 0; m < 4; ++m) {
#pragma unroll
    for (int n = 0; n < 4; ++n) {
#pragma unroll
      for (int j = 0; j < 4; ++j) {
        int r = tm + wr + m * 16 + (l >> 4) * 4 + j;
        int c = tn + wc + n * 16 + lr;
        float v = acc[m][n][j];
        if constexpr (sizeof(OutT) == 2)
          C[(size_t)r * N + c] = (OutT)f2b(v);
        else
          C[(size_t)r * N + c] = v;
      }
    }
  }
}

// ---------------- per-token 16-head attention over head axis ----------------
// 1 wave per token; qkv row = [q(1024) | k(1024) | v(1024)] bf16.
__global__ __launch_bounds__(256, 4) void attn16(
    const unsigned short* __restrict__ qkv, unsigned short* __restrict__ out) {
  __shared__ unsigned short P[4][16 * 16];
  const int t = threadIdx.x, w = t >> 6, l = t & 63;
  const int tok = blockIdx.x * 4 + w;
  const unsigned short* q = qkv + (size_t)tok * 3072;
  const unsigned short* kp = q + 1024;
  const unsigned short* vp = q + 2048;
  const int lr = l & 15, lk = (l >> 4) * 8;
  // Q,K fragments directly from global (A/B layout of 16x16x32)
  bf16x8 aq0 = *reinterpret_cast<const bf16x8*>(q + lr * 64 + lk);
  bf16x8 aq1 = *reinterpret_cast<const bf16x8*>(q + lr * 64 + 32 + lk);
  bf16x8 bk0 = *reinterpret_cast<const bf16x8*>(kp + lr * 64 + lk);
  bf16x8 bk1 = *reinterpret_cast<const bf16x8*>(kp + lr * 64 + 32 + lk);
  f32x4 s = {};
  s = mfma16(aq0, bk0, s);
  s = mfma16(aq1, bk1, s);
  // softmax over g (= lane within 16-lane group); row h = (l>>4)*4+j
  const float cexp = 0.125f * 1.44269504f;
  float p[4];
#pragma unroll
  for (int j = 0; j < 4; ++j) {
    float m = s[j];
    m = fmaxf(m, __shfl_xor(m, 1));
    m = fmaxf(m, __shfl_xor(m, 2));
    m = fmaxf(m, __shfl_xor(m, 4));
    m = fmaxf(m, __shfl_xor(m, 8));
    float e = exp2f((s[j] - m) * cexp);
    float sum = e;
    sum += __shfl_xor(sum, 1);
    sum += __shfl_xor(sum, 2);
    sum += __shfl_xor(sum, 4);
    sum += __shfl_xor(sum, 8);
    p[j] = e / sum;
  }
  unsigned short* Pw = P[w];
#pragma unroll
  for (int j = 0; j < 4; ++j) Pw[((l >> 4) * 4 + j) * 16 + lr] = f2b(p[j]);
  __syncthreads();
  ushort8 zz = {0, 0, 0, 0, 0, 0, 0, 0};
  bf16x8 ap = __builtin_bit_cast(bf16x8, zz);
  bf16x8 bv[4];
#pragma unroll
  for (int b = 0; b < 4; ++b) bv[b] = ap;
  if (l < 32) {  // k = lk + j < 16 only on lower half-wave
    ap = *reinterpret_cast<const bf16x8*>(&Pw[lr * 16 + lk]);
#pragma unroll
    for (int b = 0; b < 4; ++b) {
      ushort8 tmp;
#pragma unroll
      for (int j = 0; j < 8; ++j) tmp[j] = vp[(lk + j) * 64 + b * 16 + lr];
      bv[b] = __builtin_bit_cast(bf16x8, tmp);
    }
  }
  f32x4 o[4] = {};
#pragma unroll
  for (int b = 0; b < 4; ++b) o[b] = mfma16(ap, bv[b], o[b]);
  unsigned short* op = out + (size_t)tok * 1024;
#pragma unroll
  for (int b = 0; b < 4; ++b)
#pragma unroll
    for (int j = 0; j < 4; ++j)
      op[((l >> 4) * 4 + j) * 64 + b * 16 + lr] = f2b(o[b][j]);
}

// ---------------------------------------------------------------------------
extern "C" void kernel_launch(void* const* d_in, const int* in_sizes, int n_in,
                              void* d_out, int out_size, void* d_ws, size_t ws_size,
                              hipStream_t stream) {
  const float* x = (const float*)d_in[0];
  const float* Wq = (const float*)d_in[1];
  const float* Wk = (const float*)d_in[2];
  const float* Wv = (const float*)d_in[3];
  const float* Wo = (const float*)d_in[4];

  unsigned short* xb = (unsigned short*)d_ws;            // 64M elems (128 MB)
  unsigned short* wqkv = xb + (size_t)NTOK * E;          // 3M (6 MB)
  unsigned short* wo = wqkv + (size_t)3 * E * E;         // 1M (2 MB)
  unsigned short* qkv = wo + (size_t)E * E;              // 192M (384 MB)
  unsigned short* att = qkv + (size_t)NTOK * 3 * E;      // 64M (128 MB)

  cvt8<<<(NTOK * E / 8) / 256, 256, 0, stream>>>(x, xb, NTOK * E / 8);
  cvt8<<<(E * E / 8) / 256, 256, 0, stream>>>(Wq, wqkv, E * E / 8);
  cvt8<<<(E * E / 8) / 256, 256, 0, stream>>>(Wk, wqkv + E * E, E * E / 8);
  cvt8<<<(E * E / 8) / 256, 256, 0, stream>>>(Wv, wqkv + 2 * E * E, E * E / 8);
  cvt8<<<(E * E / 8) / 256, 256, 0, stream>>>(Wo, wo, E * E / 8);

  gemm_bt<unsigned short><<<dim3(3 * E / 128, NTOK / 128), 256, 0, stream>>>(
      xb, wqkv, qkv, NTOK, 3 * E, E);

  attn16<<<NTOK / 4, 256, 0, stream>>>(qkv, att);

  gemm_bt<float><<<dim3(E / 128, NTOK / 128), 256, 0, stream>>>(
      att, wo, (float*)d_out, NTOK, E, E);
}

// Round 2
// 771.451 us; speedup vs baseline: 1.2035x; 1.2035x over previous
//
#include <hip/hip_runtime.h>
#include <hip/hip_bf16.h>
#include <cstdint>

#define DEV static __device__ __forceinline__

typedef __attribute__((ext_vector_type(8))) __bf16 bf16x8;
typedef __attribute__((ext_vector_type(4))) float f32x4;
typedef __attribute__((ext_vector_type(8))) unsigned short ushort8;

constexpr int NTOK = 65536;
constexpr int E = 1024;

DEV unsigned short f2b(float f) {
  unsigned int u = __builtin_bit_cast(unsigned int, f);
  u += 0x7fffu + ((u >> 16) & 1u);
  return (unsigned short)(u >> 16);
}

DEV f32x4 mfma16(bf16x8 a, bf16x8 b, f32x4 c) {
  return __builtin_amdgcn_mfma_f32_16x16x32_bf16(a, b, c, 0, 0, 0);
}

DEV void gload16(const void* g, const void* l) {
  __builtin_amdgcn_global_load_lds(
      (const __attribute__((address_space(1))) void*)g,
      (__attribute__((address_space(3))) void*)l, 16, 0, 0);
}

DEV void BAR() {
  asm volatile("" ::: "memory");
  __builtin_amdgcn_s_barrier();
  asm volatile("" ::: "memory");
  __builtin_amdgcn_sched_barrier(0);
}

#define WAITVM(n_) do { \
  asm volatile("s_waitcnt vmcnt(" #n_ ")" ::: "memory"); \
  __builtin_amdgcn_sched_barrier(0); \
} while (0)

// ---------------- fp32 -> bf16 convert, 8 elems/thread ----------------
__global__ void cvt8(const float* __restrict__ in, unsigned short* __restrict__ out,
                     int n8) {
  int i = blockIdx.x * blockDim.x + threadIdx.x;
  if (i >= n8) return;
  const float4* p = (const float4*)(in + (size_t)i * 8);
  float4 a = p[0], b = p[1];
  ushort8 r;
  r[0] = f2b(a.x); r[1] = f2b(a.y); r[2] = f2b(a.z); r[3] = f2b(a.w);
  r[4] = f2b(b.x); r[5] = f2b(b.y); r[6] = f2b(b.z); r[7] = f2b(b.w);
  *(ushort8*)(out + (size_t)i * 8) = r;
}

// ---------------------------------------------------------------------------
// 256x256-tile, BK=64, 8-wave (2Mx4N) 4-phase/K-tile GEMM: C[M,N]=A[M,K]*B[N,K]^T
// T2 swizzle (XOR row&7 into 16B-slot, pre-swizzled global source + swizzled
// ds_read), T3/T4 counted vmcnt(6) (3 half-tiles in flight, never drain in
// loop), T5 setprio around MFMA, T1 XCD-aware block swizzle.
// LDS 128 KiB: A[2 buf][2 half][128][64]bf16 @0, B same @65536.
// ---------------------------------------------------------------------------
template <typename OutT>
__global__ __launch_bounds__(512, 2) void gemm8(
    const unsigned short* __restrict__ A, const unsigned short* __restrict__ B,
    OutT* __restrict__ C, int M, int N, int K, int nbx) {
  __shared__ char smem[131072];
  char* sA = smem;
  char* sB = smem + 65536;

  const int NT = K >> 6;
  const int nwg = gridDim.x;
  const int cpx = nwg >> 3;
  const int wg = ((int)blockIdx.x & 7) * cpx + ((int)blockIdx.x >> 3);
  const int tm = (wg / nbx) * 256;
  const int tn = (wg % nbx) * 256;

  const int t = threadIdx.x;
  const int w = t >> 6, l = t & 63;
  const int wr = w >> 2, wc = w & 3;  // 2 x 4 wave grid
  const int lr = l & 15, q = l >> 4;

  // staging lane constants (source column pre-swizzled: slot ^ (row&7))
  const int srow = w * 8 + (l >> 3);                  // row within 64-row chunk
  const int scol = ((l & 7) ^ (l >> 3)) * 8;          // element offset in 64-col K-slice
  // ds_read lane constants (same XOR on the read side)
  const int xorv = (lr & 7) << 4;
  const int offk0 = (q * 16) ^ xorv;
  const int offk1 = (64 + q * 16) ^ xorv;
  const int aRB = wr * 8192 + lr * 128;               // A within-half row base (bytes)
  const int bRB = wc * 4096 + lr * 128;               // B within-half row base (bytes)

#define STAGE_A(tt_, h_) do { \
    const unsigned short* g_ = A + (size_t)(tm + (h_)*128 + srow) * K + (tt_)*64 + scol; \
    const char* d_ = sA + (((tt_) & 1) * 32768 + (h_)*16384 + w * 1024); \
    gload16(g_, d_); \
    gload16(g_ + (size_t)64 * K, d_ + 8192); \
  } while (0)

#define STAGE_B(tt_, h_) do { \
    const unsigned short* g_ = B + (size_t)(tn + (h_)*128 + srow) * K + (tt_)*64 + scol; \
    const char* d_ = sB + (((tt_) & 1) * 32768 + (h_)*16384 + w * 1024); \
    gload16(g_, d_); \
    gload16(g_ + (size_t)64 * K, d_ + 8192); \
  } while (0)

  f32x4 acc[8][4] = {};
  bf16x8 af[4][2];
  bf16x8 bf_[2][2][2];

#define LDA(BUFO_, mh_) do { \
    _Pragma("unroll") for (int m_ = 0; m_ < 4; ++m_) { \
      af[m_][0] = *(const bf16x8*)(sA + (BUFO_) + (mh_)*16384 + m_*2048 + aRB + offk0); \
      af[m_][1] = *(const bf16x8*)(sA + (BUFO_) + (mh_)*16384 + m_*2048 + aRB + offk1); \
    } \
  } while (0)

#define LDB(BUFO_, nh_) do { \
    _Pragma("unroll") for (int n_ = 0; n_ < 2; ++n_) { \
      bf_[nh_][n_][0] = *(const bf16x8*)(sB + (BUFO_) + (nh_)*16384 + n_*2048 + bRB + offk0); \
      bf_[nh_][n_][1] = *(const bf16x8*)(sB + (BUFO_) + (nh_)*16384 + n_*2048 + bRB + offk1); \
    } \
  } while (0)

#define MM(mh_, nh_) do { \
    __builtin_amdgcn_s_setprio(1); \
    _Pragma("unroll") for (int m_ = 0; m_ < 4; ++m_) \
      _Pragma("unroll") for (int n_ = 0; n_ < 2; ++n_) { \
        acc[(mh_)*4 + m_][(nh_)*2 + n_] = \
            mfma16(af[m_][0], bf_[nh_][n_][0], acc[(mh_)*4 + m_][(nh_)*2 + n_]); \
        acc[(mh_)*4 + m_][(nh_)*2 + n_] = \
            mfma16(af[m_][1], bf_[nh_][n_][1], acc[(mh_)*4 + m_][(nh_)*2 + n_]); \
      } \
    __builtin_amdgcn_s_setprio(0); \
  } while (0)

  // ---- prologue: tile0 all 4 half-tiles, tile1 first 3; keep 3 in flight ----
  STAGE_A(0, 0); STAGE_B(0, 0); STAGE_B(0, 1); STAGE_A(0, 1);
  if (NT > 1) {
    STAGE_A(1, 0); STAGE_B(1, 0); STAGE_B(1, 1);
    WAITVM(6);
  } else {
    WAITVM(0);
  }
  BAR();

  for (int tt = 0; tt < NT; ++tt) {
    const int BUFO = (tt & 1) * 32768;
    // phase 1: quadrant (mh0, nh0)
    LDA(BUFO, 0); LDB(BUFO, 0);
    if (tt + 1 < NT) STAGE_A(tt + 1, 1);
    BAR(); MM(0, 0); BAR();
    // phase 2: quadrant (mh0, nh1)
    LDB(BUFO, 1);
    if (tt + 2 < NT) STAGE_A(tt + 2, 0);
    BAR(); MM(0, 1); BAR();
    // phase 3: quadrant (mh1, nh0)
    LDA(BUFO, 1);
    if (tt + 2 < NT) STAGE_B(tt + 2, 0);
    BAR(); MM(1, 0); BAR();
    // phase 4: quadrant (mh1, nh1) — the one counted-vmcnt per K-tile
    if (tt + 2 < NT) {
      STAGE_B(tt + 2, 1);
      WAITVM(6);
    } else if (tt + 1 < NT) {
      WAITVM(0);
    }
    BAR(); MM(1, 1); BAR();
  }

  // ---- epilogue ----
#pragma unroll
  for (int mh = 0; mh < 2; ++mh)
#pragma unroll
    for (int m = 0; m < 4; ++m)
#pragma unroll
      for (int nh = 0; nh < 2; ++nh)
#pragma unroll
        for (int n = 0; n < 2; ++n)
#pragma unroll
          for (int j = 0; j < 4; ++j) {
            int row = tm + mh * 128 + wr * 64 + m * 16 + q * 4 + j;
            int col = tn + nh * 128 + wc * 32 + n * 16 + lr;
            float v = acc[mh * 4 + m][nh * 2 + n][j];
            if constexpr (sizeof(OutT) == 2)
              C[(size_t)row * N + col] = (OutT)f2b(v);
            else
              C[(size_t)row * N + col] = v;
          }
#undef STAGE_A
#undef STAGE_B
#undef LDA
#undef LDB
#undef MM
}

// ---------------- per-token 16-head attention over head axis ----------------
__global__ __launch_bounds__(256, 4) void attn16(
    const unsigned short* __restrict__ qkv, unsigned short* __restrict__ out) {
  __shared__ unsigned short P[4][16 * 16];
  const int t = threadIdx.x, w = t >> 6, l = t & 63;
  const int tok = blockIdx.x * 4 + w;
  const unsigned short* q = qkv + (size_t)tok * 3072;
  const unsigned short* kp = q + 1024;
  const unsigned short* vp = q + 2048;
  const int lr = l & 15, lk = (l >> 4) * 8;
  bf16x8 aq0 = *reinterpret_cast<const bf16x8*>(q + lr * 64 + lk);
  bf16x8 aq1 = *reinterpret_cast<const bf16x8*>(q + lr * 64 + 32 + lk);
  bf16x8 bk0 = *reinterpret_cast<const bf16x8*>(kp + lr * 64 + lk);
  bf16x8 bk1 = *reinterpret_cast<const bf16x8*>(kp + lr * 64 + 32 + lk);
  f32x4 s = {};
  s = mfma16(aq0, bk0, s);
  s = mfma16(aq1, bk1, s);
  const float cexp = 0.125f * 1.44269504f;
  float p[4];
#pragma unroll
  for (int j = 0; j < 4; ++j) {
    float m = s[j];
    m = fmaxf(m, __shfl_xor(m, 1));
    m = fmaxf(m, __shfl_xor(m, 2));
    m = fmaxf(m, __shfl_xor(m, 4));
    m = fmaxf(m, __shfl_xor(m, 8));
    float e = exp2f((s[j] - m) * cexp);
    float sum = e;
    sum += __shfl_xor(sum, 1);
    sum += __shfl_xor(sum, 2);
    sum += __shfl_xor(sum, 4);
    sum += __shfl_xor(sum, 8);
    p[j] = e / sum;
  }
  unsigned short* Pw = P[w];
#pragma unroll
  for (int j = 0; j < 4; ++j) Pw[((l >> 4) * 4 + j) * 16 + lr] = f2b(p[j]);
  __syncthreads();
  ushort8 zz = {0, 0, 0, 0, 0, 0, 0, 0};
  bf16x8 ap = __builtin_bit_cast(bf16x8, zz);
  bf16x8 bv[4];
#pragma unroll
  for (int b = 0; b < 4; ++b) bv[b] = ap;
  if (l < 32) {
    ap = *reinterpret_cast<const bf16x8*>(&Pw[lr * 16 + lk]);
#pragma unroll
    for (int b = 0; b < 4; ++b) {
      ushort8 tmp;
#pragma unroll
      for (int j = 0; j < 8; ++j) tmp[j] = vp[(lk + j) * 64 + b * 16 + lr];
      bv[b] = __builtin_bit_cast(bf16x8, tmp);
    }
  }
  f32x4 o[4] = {};
#pragma unroll
  for (int b = 0; b < 4; ++b) o[b] = mfma16(ap, bv[b], o[b]);
  unsigned short* op = out + (size_t)tok * 1024;
#pragma unroll
  for (int b = 0; b < 4; ++b)
#pragma unroll
    for (int j = 0; j < 4; ++j)
      op[((l >> 4) * 4 + j) * 64 + b * 16 + lr] = f2b(o[b][j]);
}

// ---------------------------------------------------------------------------
extern "C" void kernel_launch(void* const* d_in, const int* in_sizes, int n_in,
                              void* d_out, int out_size, void* d_ws, size_t ws_size,
                              hipStream_t stream) {
  const float* x = (const float*)d_in[0];
  const float* Wq = (const float*)d_in[1];
  const float* Wk = (const float*)d_in[2];
  const float* Wv = (const float*)d_in[3];
  const float* Wo = (const float*)d_in[4];

  unsigned short* xb = (unsigned short*)d_ws;            // 64M elems (128 MB)
  unsigned short* wqkv = xb + (size_t)NTOK * E;          // 3M (6 MB)
  unsigned short* wo = wqkv + (size_t)3 * E * E;         // 1M (2 MB)
  unsigned short* qkv = wo + (size_t)E * E;              // 192M (384 MB)
  unsigned short* att = qkv + (size_t)NTOK * 3 * E;      // 64M (128 MB)

  cvt8<<<(NTOK * E / 8) / 256, 256, 0, stream>>>(x, xb, NTOK * E / 8);
  cvt8<<<(E * E / 8) / 256, 256, 0, stream>>>(Wq, wqkv, E * E / 8);
  cvt8<<<(E * E / 8) / 256, 256, 0, stream>>>(Wk, wqkv + E * E, E * E / 8);
  cvt8<<<(E * E / 8) / 256, 256, 0, stream>>>(Wv, wqkv + 2 * E * E, E * E / 8);
  cvt8<<<(E * E / 8) / 256, 256, 0, stream>>>(Wo, wo, E * E / 8);

  // QKV: [65536,1024] x [3072,1024]^T -> [65536,3072]
  gemm8<unsigned short><<<(NTOK / 256) * (3 * E / 256), 512, 0, stream>>>(
      xb, wqkv, qkv, NTOK, 3 * E, E, 3 * E / 256);

  attn16<<<NTOK / 4, 256, 0, stream>>>(qkv, att);

  // O-proj: [65536,1024] x [1024,1024]^T -> [65536,1024] fp32
  gemm8<float><<<(NTOK / 256) * (E / 256), 512, 0, stream>>>(
      att, wo, (float*)d_out, NTOK, E, E, E / 256);
}

// Round 3
// 747.564 us; speedup vs baseline: 1.2420x; 1.0320x over previous
//
#include <hip/hip_runtime.h>
#include <hip/hip_bf16.h>
#include <cstdint>

#define DEV static __device__ __forceinline__

typedef __attribute__((ext_vector_type(8))) __bf16 bf16x8;
typedef __attribute__((ext_vector_type(4))) float f32x4;
typedef __attribute__((ext_vector_type(8))) unsigned short ushort8;

constexpr int NTOK = 65536;
constexpr int E = 1024;

DEV unsigned short f2b(float f) {
  unsigned int u = __builtin_bit_cast(unsigned int, f);
  u += 0x7fffu + ((u >> 16) & 1u);
  return (unsigned short)(u >> 16);
}

DEV f32x4 mfma16(bf16x8 a, bf16x8 b, f32x4 c) {
  return __builtin_amdgcn_mfma_f32_16x16x32_bf16(a, b, c, 0, 0, 0);
}

DEV void gload16(const void* g, const void* l) {
  __builtin_amdgcn_global_load_lds(
      (const __attribute__((address_space(1))) void*)g,
      (__attribute__((address_space(3))) void*)l, 16, 0, 0);
}

DEV void BAR() {
  asm volatile("" ::: "memory");
  __builtin_amdgcn_s_barrier();
  asm volatile("" ::: "memory");
  __builtin_amdgcn_sched_barrier(0);
}

#define WAITVM(n_) do { \
  asm volatile("s_waitcnt vmcnt(" #n_ ")" ::: "memory"); \
  __builtin_amdgcn_sched_barrier(0); \
} while (0)

#define WAITLGKM0() do { \
  asm volatile("s_waitcnt lgkmcnt(0)" ::: "memory"); \
  __builtin_amdgcn_sched_barrier(0); \
} while (0)

// ---------------- fp32 -> bf16 convert, 8 elems/thread ----------------
__global__ void cvt8(const float* __restrict__ in, unsigned short* __restrict__ out,
                     int n8) {
  int i = blockIdx.x * blockDim.x + threadIdx.x;
  if (i >= n8) return;
  const float4* p = (const float4*)(in + (size_t)i * 8);
  float4 a = p[0], b = p[1];
  ushort8 r;
  r[0] = f2b(a.x); r[1] = f2b(a.y); r[2] = f2b(a.z); r[3] = f2b(a.w);
  r[4] = f2b(b.x); r[5] = f2b(b.y); r[6] = f2b(b.z); r[7] = f2b(b.w);
  *(ushort8*)(out + (size_t)i * 8) = r;
}

// ---------------------------------------------------------------------------
// 256x256-tile, BK=64, 8-wave (2Mx4N), 8 phases / 2 K-tiles with compile-time
// constant LDS offsets (m201 template). T1 XCD swizzle, T2 st-swizzle
// (pre-swizzled global source + XOR'd ds_read), T3/T4 counted vmcnt(6),
// T5 setprio. LDS 128 KiB: A[2buf][2half][128][64]bf16 @0, B same @65536.
// Requires K % 128 == 0 (NT even, >= 2).
// ---------------------------------------------------------------------------
template <typename OutT>
__global__ __launch_bounds__(512, 2) void gemm8(
    const unsigned short* __restrict__ A, const unsigned short* __restrict__ B,
    OutT* __restrict__ C, int M, int N, int K, int nbx) {
  __shared__ char smem[131072];
  char* sA = smem;
  char* sB = smem + 65536;

  const int NT = K >> 6;
  const int nwg = gridDim.x;
  const int cpx = nwg >> 3;
  const int wg = ((int)blockIdx.x & 7) * cpx + ((int)blockIdx.x >> 3);
  const int tm = (wg / nbx) * 256;
  const int tn = (wg % nbx) * 256;

  const int t = threadIdx.x;
  const int w = t >> 6, l = t & 63;
  const int wr = w >> 2, wc = w & 3;  // 2 x 4 wave grid
  const int lr = l & 15, q = l >> 4;

  // staging lane constants (source column pre-swizzled: slot ^ (row&7))
  const int srow = w * 8 + (l >> 3);
  const int scol = ((l & 7) ^ (l >> 3)) * 8;
  // ds_read lane constants (same XOR on the read side)
  const int xorv = (lr & 7) << 4;
  const int offk0 = (q * 16) ^ xorv;
  const int offk1 = (64 + q * 16) ^ xorv;
  const int aRB = wr * 8192 + lr * 128;
  const int bRB = wc * 4096 + lr * 128;

#define STAGE_A(tt_, h_) do { \
    const unsigned short* g_ = A + (size_t)(tm + (h_)*128 + srow) * K + (tt_)*64 + scol; \
    const char* d_ = sA + (((tt_) & 1) * 32768 + (h_)*16384 + w * 1024); \
    gload16(g_, d_); \
    gload16(g_ + (size_t)64 * K, d_ + 8192); \
  } while (0)

#define STAGE_B(tt_, h_) do { \
    const unsigned short* g_ = B + (size_t)(tn + (h_)*128 + srow) * K + (tt_)*64 + scol; \
    const char* d_ = sB + (((tt_) & 1) * 32768 + (h_)*16384 + w * 1024); \
    gload16(g_, d_); \
    gload16(g_ + (size_t)64 * K, d_ + 8192); \
  } while (0)

  f32x4 acc[8][4] = {};
  bf16x8 af[4][2];
  bf16x8 bf_[2][2][2];

  // buf_ and half indices are compile-time literals -> constant LDS offsets
#define LDA(buf_, mh_) do { \
    _Pragma("unroll") for (int m_ = 0; m_ < 4; ++m_) { \
      af[m_][0] = *(const bf16x8*)(sA + (buf_)*32768 + (mh_)*16384 + m_*2048 + aRB + offk0); \
      af[m_][1] = *(const bf16x8*)(sA + (buf_)*32768 + (mh_)*16384 + m_*2048 + aRB + offk1); \
    } \
  } while (0)

#define LDB(buf_, nh_) do { \
    _Pragma("unroll") for (int n_ = 0; n_ < 2; ++n_) { \
      bf_[nh_][n_][0] = *(const bf16x8*)(sB + (buf_)*32768 + (nh_)*16384 + n_*2048 + bRB + offk0); \
      bf_[nh_][n_][1] = *(const bf16x8*)(sB + (buf_)*32768 + (nh_)*16384 + n_*2048 + bRB + offk1); \
    } \
  } while (0)

#define MM(mh_, nh_) do { \
    __builtin_amdgcn_s_setprio(1); \
    _Pragma("unroll") for (int m_ = 0; m_ < 4; ++m_) \
      _Pragma("unroll") for (int n_ = 0; n_ < 2; ++n_) { \
        acc[(mh_)*4 + m_][(nh_)*2 + n_] = \
            mfma16(af[m_][0], bf_[nh_][n_][0], acc[(mh_)*4 + m_][(nh_)*2 + n_]); \
        acc[(mh_)*4 + m_][(nh_)*2 + n_] = \
            mfma16(af[m_][1], bf_[nh_][n_][1], acc[(mh_)*4 + m_][(nh_)*2 + n_]); \
      } \
    __builtin_amdgcn_s_setprio(0); \
  } while (0)

  // ---- prologue: tile0 fully, tile1 first 3 half-tiles; drain tile0 ----
  STAGE_A(0, 0); STAGE_B(0, 0); STAGE_B(0, 1); STAGE_A(0, 1);
  STAGE_A(1, 0); STAGE_B(1, 0); STAGE_B(1, 1);
  WAITVM(6);
  BAR();

  int T = 0;
  // ---- steady state: branch-free, 2 K-tiles per iteration ----
  for (; T + 3 < NT; T += 2) {
    // ph1: tile T quad(0,0)
    LDA(0, 0); LDB(0, 0);
    STAGE_A(T + 1, 1);
    BAR(); MM(0, 0); BAR();
    // ph2
    LDB(0, 1);
    STAGE_A(T + 2, 0);
    BAR(); MM(0, 1); BAR();
    // ph3
    LDA(0, 1);
    STAGE_B(T + 2, 0);
    BAR(); MM(1, 0); BAR();
    // ph4
    STAGE_B(T + 2, 1);
    WAITVM(6);
    BAR(); MM(1, 1); BAR();
    // ph5: tile T+1 quad(0,0)
    LDA(1, 0); LDB(1, 0);
    STAGE_A(T + 2, 1);
    BAR(); MM(0, 0); BAR();
    // ph6
    LDB(1, 1);
    STAGE_A(T + 3, 0);
    BAR(); MM(0, 1); BAR();
    // ph7
    LDA(1, 1);
    STAGE_B(T + 3, 0);
    BAR(); MM(1, 0); BAR();
    // ph8
    STAGE_B(T + 3, 1);
    WAITVM(6);
    BAR(); MM(1, 1); BAR();
  }
  // ---- tail: last 2 tiles (T == NT-2) ----
  {
    LDA(0, 0); LDB(0, 0);
    STAGE_A(T + 1, 1);
    BAR(); MM(0, 0); BAR();
    LDB(0, 1);
    BAR(); MM(0, 1); BAR();
    LDA(0, 1);
    BAR(); MM(1, 0); BAR();
    WAITVM(0);
    BAR(); MM(1, 1); BAR();
    LDA(1, 0); LDB(1, 0);
    BAR(); MM(0, 0); BAR();
    LDB(1, 1);
    BAR(); MM(0, 1); BAR();
    LDA(1, 1);
    BAR(); MM(1, 0); BAR();
    BAR(); MM(1, 1); BAR();
  }

  // ---- epilogue ----
#pragma unroll
  for (int mh = 0; mh < 2; ++mh)
#pragma unroll
    for (int m = 0; m < 4; ++m)
#pragma unroll
      for (int nh = 0; nh < 2; ++nh)
#pragma unroll
        for (int n = 0; n < 2; ++n)
#pragma unroll
          for (int j = 0; j < 4; ++j) {
            int row = tm + mh * 128 + wr * 64 + m * 16 + q * 4 + j;
            int col = tn + nh * 128 + wc * 32 + n * 16 + lr;
            float v = acc[mh * 4 + m][nh * 2 + n][j];
            if constexpr (sizeof(OutT) == 2)
              C[(size_t)row * N + col] = (OutT)f2b(v);
            else
              C[(size_t)row * N + col] = v;
          }
#undef STAGE_A
#undef STAGE_B
#undef LDA
#undef LDB
#undef MM
}

// ---------------- per-token 16-head attention over head axis ----------------
__global__ __launch_bounds__(256, 4) void attn16(
    const unsigned short* __restrict__ qkv, unsigned short* __restrict__ out) {
  __shared__ unsigned short P[4][16 * 16];
  const int t = threadIdx.x, w = t >> 6, l = t & 63;
  const int tok = blockIdx.x * 4 + w;
  const unsigned short* q = qkv + (size_t)tok * 3072;
  const unsigned short* kp = q + 1024;
  const unsigned short* vp = q + 2048;
  const int lr = l & 15, lk = (l >> 4) * 8;
  bf16x8 aq0 = *reinterpret_cast<const bf16x8*>(q + lr * 64 + lk);
  bf16x8 aq1 = *reinterpret_cast<const bf16x8*>(q + lr * 64 + 32 + lk);
  bf16x8 bk0 = *reinterpret_cast<const bf16x8*>(kp + lr * 64 + lk);
  bf16x8 bk1 = *reinterpret_cast<const bf16x8*>(kp + lr * 64 + 32 + lk);
  f32x4 s = {};
  s = mfma16(aq0, bk0, s);
  s = mfma16(aq1, bk1, s);
  const float cexp = 0.125f * 1.44269504f;
  float p[4];
#pragma unroll
  for (int j = 0; j < 4; ++j) {
    float m = s[j];
    m = fmaxf(m, __shfl_xor(m, 1));
    m = fmaxf(m, __shfl_xor(m, 2));
    m = fmaxf(m, __shfl_xor(m, 4));
    m = fmaxf(m, __shfl_xor(m, 8));
    float e = exp2f((s[j] - m) * cexp);
    float sum = e;
    sum += __shfl_xor(sum, 1);
    sum += __shfl_xor(sum, 2);
    sum += __shfl_xor(sum, 4);
    sum += __shfl_xor(sum, 8);
    p[j] = e / sum;
  }
  unsigned short* Pw = P[w];
#pragma unroll
  for (int j = 0; j < 4; ++j) Pw[((l >> 4) * 4 + j) * 16 + lr] = f2b(p[j]);
  // P tile is wave-private: per-wave LDS visibility needs only lgkmcnt(0)
  WAITLGKM0();
  ushort8 zz = {0, 0, 0, 0, 0, 0, 0, 0};
  bf16x8 ap = __builtin_bit_cast(bf16x8, zz);
  bf16x8 bv[4];
#pragma unroll
  for (int b = 0; b < 4; ++b) bv[b] = ap;
  if (l < 32) {
    ap = *reinterpret_cast<const bf16x8*>(&Pw[lr * 16 + lk]);
#pragma unroll
    for (int b = 0; b < 4; ++b) {
      ushort8 tmp;
#pragma unroll
      for (int j = 0; j < 8; ++j) tmp[j] = vp[(lk + j) * 64 + b * 16 + lr];
      bv[b] = __builtin_bit_cast(bf16x8, tmp);
    }
  }
  f32x4 o[4] = {};
#pragma unroll
  for (int b = 0; b < 4; ++b) o[b] = mfma16(ap, bv[b], o[b]);
  unsigned short* op = out + (size_t)tok * 1024;
#pragma unroll
  for (int b = 0; b < 4; ++b)
#pragma unroll
    for (int j = 0; j < 4; ++j)
      op[((l >> 4) * 4 + j) * 64 + b * 16 + lr] = f2b(o[b][j]);
}

// ---------------------------------------------------------------------------
extern "C" void kernel_launch(void* const* d_in, const int* in_sizes, int n_in,
                              void* d_out, int out_size, void* d_ws, size_t ws_size,
                              hipStream_t stream) {
  const float* x = (const float*)d_in[0];
  const float* Wq = (const float*)d_in[1];
  const float* Wk = (const float*)d_in[2];
  const float* Wv = (const float*)d_in[3];
  const float* Wo = (const float*)d_in[4];

  unsigned short* xb = (unsigned short*)d_ws;            // 64M elems (128 MB)
  unsigned short* wqkv = xb + (size_t)NTOK * E;          // 3M (6 MB)
  unsigned short* wo = wqkv + (size_t)3 * E * E;         // 1M (2 MB)
  unsigned short* qkv = wo + (size_t)E * E;              // 192M (384 MB)
  unsigned short* att = qkv + (size_t)NTOK * 3 * E;      // 64M (128 MB)

  cvt8<<<(NTOK * E / 8) / 256, 256, 0, stream>>>(x, xb, NTOK * E / 8);
  cvt8<<<(E * E / 8) / 256, 256, 0, stream>>>(Wq, wqkv, E * E / 8);
  cvt8<<<(E * E / 8) / 256, 256, 0, stream>>>(Wk, wqkv + E * E, E * E / 8);
  cvt8<<<(E * E / 8) / 256, 256, 0, stream>>>(Wv, wqkv + 2 * E * E, E * E / 8);
  cvt8<<<(E * E / 8) / 256, 256, 0, stream>>>(Wo, wo, E * E / 8);

  // QKV: [65536,1024] x [3072,1024]^T -> [65536,3072]
  gemm8<unsigned short><<<(NTOK / 256) * (3 * E / 256), 512, 0, stream>>>(
      xb, wqkv, qkv, NTOK, 3 * E, E, 3 * E / 256);

  attn16<<<NTOK / 4, 256, 0, stream>>>(qkv, att);

  // O-proj: [65536,1024] x [1024,1024]^T -> [65536,1024] fp32
  gemm8<float><<<(NTOK / 256) * (E / 256), 512, 0, stream>>>(
      att, wo, (float*)d_out, NTOK, E, E, E / 256);
}